// Round 1
// 343.920 us; speedup vs baseline: 1.0084x; 1.0084x over previous
//
#include <hip/hip_runtime.h>

// BMM_S8T_S8N_F16T: out[b,m,n] = fp16-range(alpha * sum_k A[b,m,k]*B[b,n,k])
// A: (B,M,K) int32 (int8-range), B: (B,N,K) int32, out: float. B=64, M=N=1024, K=128.
//
// Roofline: 268 MB write + 67 MB read => ~53 us @6.3 TB/s. Write-dominated.
// Harness poison fill (1 GiB @ ~5.8 TB/s ~= 190 us) is fixed overhead on top.
// R5 (347 us harness, ~157 us kernel): per-iter __syncthreads forced
//   s_waitcnt vmcnt(0) drain of prefetch loads AND store-acks each iter,
//   re-aligning all 4 waves; store pipe duty cycle ~1/3.
// R6: BARRIER-FREE main loop. Wave tiling per iter changed 2m x 2n ->
//   4 waves x (128m x 32n): each wave consumes ONLY its own 32 B-rows, so B
//   staging is wave-private (own LDS slice, own double-buffer). No cross-wave
//   hazard -> zero __syncthreads in the loop. Per-wave flow on data deps only:
//   issue B(ni+1) loads -> MFMA (lgkm deps) -> stores (never awaited) ->
//   pack (vmcnt waits own loads; younger stores stay in flight) -> next iter.
//   8 free-running store streams/CU keep writes continuous.

#define Mdim 1024
#define Ndim 1024
#define Kdim 128
#define TILE 128
#define LDS_STRIDE 144  // 128B row + 16B pad; all access patterns <=2-way bank alias

using int32x4 = __attribute__((ext_vector_type(4))) int;
using floatx4 = __attribute__((ext_vector_type(4))) float;

__device__ __forceinline__ unsigned pack8(int32x4 v) {
    return (unsigned)(v.x & 255) | ((unsigned)(v.y & 255) << 8)
         | ((unsigned)(v.z & 255) << 16) | ((unsigned)(v.w & 255) << 24);
}

__global__ __launch_bounds__(256)
void bmm_s8_kernel(const int* __restrict__ A, const int* __restrict__ Bm,
                   const float* __restrict__ alpha_p, float* __restrict__ out)
{
    __shared__ unsigned char As[TILE * LDS_STRIDE];
    __shared__ unsigned char Bs[2][TILE * LDS_STRIDE];  // rows [w*32, w*32+32) owned by wave w

    const int t  = threadIdx.x;
    const int z  = blockIdx.x;   // batch; linear%8 == z%8 -> per-XCD batch affinity
    const int m0 = blockIdx.y * TILE;

    const int* __restrict__ Ab = A  + (size_t)z * Mdim * Kdim + (size_t)m0 * Kdim;
    const int* __restrict__ Bb = Bm + (size_t)z * Ndim * Kdim;

    const int lane = t & 63;
    const int wave = t >> 6;
    const int wn   = wave * 32;  // this wave's private n-band within each tile

    // ---- prologue: stage A (all threads) + B tile 0 (per-wave, own rows) ----
    {
        int32x4 areg[16], breg[16];
#pragma unroll
        for (int j = 0; j < 16; ++j) {
            const int f    = t + 256 * j;
            const int row  = f >> 5;
            const int colb = (f & 31) * 4;
            areg[j] = *(const int32x4*)(Ab + (size_t)row * Kdim + colb);
        }
#pragma unroll
        for (int j = 0; j < 16; ++j) {
            const int f    = lane + 64 * j;
            const int rl   = f >> 5;            // 0..31 within the wave's band
            const int colb = (f & 31) * 4;
            breg[j] = *(const int32x4*)(Bb + (size_t)(wn + rl) * Kdim + colb);
        }
#pragma unroll
        for (int j = 0; j < 16; ++j) {
            const int f    = t + 256 * j;
            const int row  = f >> 5;
            const int colb = (f & 31) * 4;
            *(unsigned*)(&As[row * LDS_STRIDE + colb]) = pack8(areg[j]);
        }
#pragma unroll
        for (int j = 0; j < 16; ++j) {
            const int f    = lane + 64 * j;
            const int rl   = f >> 5;
            const int colb = (f & 31) * 4;
            *(unsigned*)(&Bs[0][(wn + rl) * LDS_STRIDE + colb]) = pack8(breg[j]);
        }
    }
    __syncthreads();  // the ONLY barrier: A visibility (B slices are wave-private)

    const float alpha = alpha_p[0];
    const int lrow = lane & 15;
    const int koff = (lane >> 4) * 16;
    const int cm   = lane & 15;        // D col = m_local
    const int cn   = (lane >> 4) * 4;  // D rows = 4 consecutive n_local
    float* __restrict__ Ob = out + (size_t)z * Mdim * Ndim;

#pragma unroll 1
    for (int ni = 0; ni < 8; ++ni) {
        const int buf = ni & 1;

        // ---- issue next B tile's loads for OUR band (stay in flight across
        //      MFMA + stores; pack below waits only on these via data dep) ----
        int32x4 breg[16];
        if (ni < 7) {
            const int* __restrict__ Bt = Bb + (size_t)(ni + 1) * TILE * Kdim;
#pragma unroll
            for (int j = 0; j < 16; ++j) {
                const int f    = lane + 64 * j;
                const int rl   = f >> 5;
                const int colb = (f & 31) * 4;
                breg[j] = *(const int32x4*)(Bt + (size_t)(wn + rl) * Kdim + colb);
            }
        }

        // ---- MFMA: wave computes 128(m) x 32(n) of this tile ----
        int32x4 acc[8][2];
#pragma unroll
        for (int mt = 0; mt < 8; ++mt)
#pragma unroll
            for (int nt = 0; nt < 2; ++nt)
                acc[mt][nt] = (int32x4){0, 0, 0, 0};

#pragma unroll
        for (int ks = 0; ks < 2; ++ks) {
            int32x4 af[8], bf[2];
#pragma unroll
            for (int mt = 0; mt < 8; ++mt)
                af[mt] = *(const int32x4*)(&As[(mt * 16 + lrow) * LDS_STRIDE + ks * 64 + koff]);
#pragma unroll
            for (int nt = 0; nt < 2; ++nt)
                bf[nt] = *(const int32x4*)(&Bs[buf][(wn + nt * 16 + lrow) * LDS_STRIDE + ks * 64 + koff]);
            // swapped operands: D holds m in cols (lane&15), 4 consecutive n in regs
#pragma unroll
            for (int mt = 0; mt < 8; ++mt)
#pragma unroll
                for (int nt = 0; nt < 2; ++nt)
                    acc[mt][nt] = __builtin_amdgcn_mfma_i32_16x16x64_i8(
                        bf[nt], af[mt], acc[mt][nt], 0, 0, 0);
        }

        // ---- epilogue: float4 stores (acks never awaited) ----
#pragma unroll
        for (int mt = 0; mt < 8; ++mt) {
            const size_t rowbase = (size_t)(m0 + mt * 16 + cm) * Ndim;
#pragma unroll
            for (int nt = 0; nt < 2; ++nt) {
                const int col = ni * TILE + wn + nt * 16 + cn;
                floatx4 v;
                v.x = alpha * (float)acc[mt][nt][0];
                v.y = alpha * (float)acc[mt][nt][1];
                v.z = alpha * (float)acc[mt][nt][2];
                v.w = alpha * (float)acc[mt][nt][3];
                *(floatx4*)(Ob + rowbase + col) = v;
            }
        }

        // ---- consume prefetch: pack into our slice of the other buffer.
        //      vmcnt waits our 16 loads only (stores are younger, stay in
        //      flight); next iter's ds_read waits lgkmcnt on these writes. ----
        if (ni < 7) {
#pragma unroll
            for (int j = 0; j < 16; ++j) {
                const int f    = lane + 64 * j;
                const int rl   = f >> 5;
                const int colb = (f & 31) * 4;
                *(unsigned*)(&Bs[buf ^ 1][(wn + rl) * LDS_STRIDE + colb]) = pack8(breg[j]);
            }
        }
    }
}

extern "C" void kernel_launch(void* const* d_in, const int* in_sizes, int n_in,
                              void* d_out, int out_size, void* d_ws, size_t ws_size,
                              hipStream_t stream) {
    const int*   a     = (const int*)d_in[0];
    const int*   b     = (const int*)d_in[1];
    const float* alpha = (const float*)d_in[2];
    float*       out   = (float*)d_out;

    const int batch = in_sizes[0] / (Mdim * Kdim);  // 64
    dim3 grid(batch, Mdim / TILE);                  // (64, 8): linear%8 == z%8
    bmm_s8_kernel<<<grid, 256, 0, stream>>>(a, b, alpha, out);
}

// Round 3
// 343.451 us; speedup vs baseline: 1.0098x; 1.0014x over previous
//
#include <hip/hip_runtime.h>

// BMM_S8T_S8N_F16T: out[b,m,n] = fp16-range(alpha * sum_k A[b,m,k]*B[b,n,k])
// A: (B,M,K) int32 (int8-range), B: (B,N,K) int32, out: float. B=64, M=N=1024, K=128.
//
// Roofline: 268 MB write + 67 MB read => ~53 us @6.3 TB/s. Write-dominated.
// R2-R6 all ~157-170 us kernel regardless of schedule (barriers, prefetch,
//   wave-private staging all neutral). Common factor: stores were 128-B lines
//   at 4096-B stride (power-of-2 row pitch) -> suspected HBM channel/bank
//   aliasing; effective write BW ~1.7 TB/s vs the fill's 5.8 TB/s linear.
// R7 (FAILED): full-row-sequential-store design, but staging loop covered only
//   256 of 1024 B rows (16 chunks/thread instead of 64) -> garbage output.
//   Timing never observed; stride theory still untested.
// R8: R7 with staging fixed (4 rounds x 16 chunks x 512 thr = 32768 chunks =
//   1024 rows). Block = (batch z, m-quarter q): full B packed int8 in LDS
//   (128 KiB, XOR-swizzled), then 16 strips of 16 m-rows; each strip writes
//   16 full 4-KB rows (64 KB contiguous), strips sequential -> one dense 1-MB
//   linear write stream per block. Grid 256 = 1 block/CU; q-siblings share
//   XCD L2 for the B stage (linear%8==z%8).

#define Mdim 1024
#define Ndim 1024
#define Kdim 128
#define NROWS 16     // m-rows per strip
#define NSTRIPS 16   // strips per block -> 256 m-rows
#define BSTRIDE 128  // packed bytes per B row (no pad; XOR swizzle instead)

using int32x4 = __attribute__((ext_vector_type(4))) int;
using floatx4 = __attribute__((ext_vector_type(4))) float;

__device__ __forceinline__ unsigned pack8(int32x4 v) {
    return (unsigned)(v.x & 255) | ((unsigned)(v.y & 255) << 8)
         | ((unsigned)(v.z & 255) << 16) | ((unsigned)(v.w & 255) << 24);
}

// XOR row&7 into the 16-B-unit bits: bijective per row; stage writes see a
// bank permutation (2 rows/wave -> 2-way alias, free); b128 reads get all 32
// banks exactly once per 8-lane group.
__device__ __forceinline__ int swz(int byte_off) {
    return byte_off ^ (((byte_off >> 7) & 7) << 4);
}

__global__ __launch_bounds__(512, 2)
void bmm_s8_kernel(const int* __restrict__ A, const int* __restrict__ Bm,
                   const float* __restrict__ alpha_p, float* __restrict__ out)
{
    __shared__ unsigned char Bs[1024 * BSTRIDE];  // 128 KiB: full B, packed int8

    const int t    = threadIdx.x;
    const int z    = blockIdx.x;   // batch; linear%8 == z%8 -> per-XCD batch affinity
    const int q    = blockIdx.y;   // m-quarter: rows [q*256, q*256+256)
    const int lane = t & 63;
    const int wave = t >> 6;       // 0..7
    const int wn   = wave * 128;   // this wave's n band

    const int* __restrict__ Ab = A  + (size_t)z * Mdim * Kdim + (size_t)(q * 256) * Kdim;
    const int* __restrict__ Bb = Bm + (size_t)z * Ndim * Kdim;
    float* __restrict__ Ob     = out + (size_t)z * Mdim * Ndim + (size_t)(q * 256) * Ndim;

    const int r = lane & 15;   // fragment row within 16
    const int g = lane >> 4;   // fragment k-chunk selector

    // ---- issue A prefetch for strip 0 (oldest loads; land during staging) ----
    // af frag (ks): lane holds A[row=r][k = ks*64 + g*16 .. +15]; load k=(ks,i)
    // covers int32s ks*64 + g*16 + i*4 .. +3.
    int32x4 araw[8];
#pragma unroll
    for (int k = 0; k < 8; ++k) {
        const int ks = k >> 2, i = k & 3;
        araw[k] = *(const int32x4*)(Ab + (size_t)r * Kdim + ks * 64 + g * 16 + i * 4);
    }

    // ---- stage FULL B (1024 rows x 32 16-B chunks = 32768 chunks) ----
    // 512 threads x 64 chunks, in 4 rounds of {16 loads, 16 packed stores}.
#pragma unroll 1
    for (int rr = 0; rr < 4; ++rr) {
        int32x4 breg[16];
#pragma unroll
        for (int j = 0; j < 16; ++j) {
            const int f    = t + 512 * (rr * 16 + j);
            const int row  = f >> 5;             // 0..1023 across rounds
            const int colb = (f & 31) * 4;       // int32 col == packed byte offset
            breg[j] = *(const int32x4*)(Bb + (size_t)row * Kdim + colb);
        }
#pragma unroll
        for (int j = 0; j < 16; ++j) {
            const int f    = t + 512 * (rr * 16 + j);
            const int row  = f >> 5;
            const int colb = (f & 31) * 4;
            *(unsigned*)(&Bs[swz(row * BSTRIDE + colb)]) = pack8(breg[j]);
        }
    }
    __syncthreads();

    const float alpha = alpha_p[0];
    const int cm = lane & 15;        // D col = m_local
    const int cn = (lane >> 4) * 4;  // D rows = 4 consecutive n_local

#pragma unroll 1
    for (int s = 0; s < NSTRIPS; ++s) {
        // consume prefetched A into fragments (loads long since landed)
        int32x4 af[2];
#pragma unroll
        for (int ks = 0; ks < 2; ++ks)
            af[ks] = (int32x4){ (int)pack8(araw[ks * 4 + 0]), (int)pack8(araw[ks * 4 + 1]),
                                (int)pack8(araw[ks * 4 + 2]), (int)pack8(araw[ks * 4 + 3]) };

        // issue next strip's A loads (in flight across compute + stores)
        if (s + 1 < NSTRIPS) {
            const int* __restrict__ An = Ab + (size_t)((s + 1) * NROWS) * Kdim;
#pragma unroll
            for (int k = 0; k < 8; ++k) {
                const int ks = k >> 2, i = k & 3;
                araw[k] = *(const int32x4*)(An + (size_t)r * Kdim + ks * 64 + g * 16 + i * 4);
            }
        }

        // ---- MFMA: wave computes 16(m) x 128(n) of this strip ----
        int32x4 acc[8];
#pragma unroll
        for (int nt = 0; nt < 8; ++nt)
            acc[nt] = (int32x4){0, 0, 0, 0};

#pragma unroll
        for (int ks = 0; ks < 2; ++ks) {
#pragma unroll
            for (int nt = 0; nt < 8; ++nt) {
                const int row = wn + nt * 16 + r;
                int32x4 bf = *(const int32x4*)(&Bs[swz(row * BSTRIDE + ks * 64 + g * 16)]);
                // swapped operands: D holds m in cols (lane&15), 4 consecutive n in regs
                acc[nt] = __builtin_amdgcn_mfma_i32_16x16x64_i8(bf, af[ks], acc[nt], 0, 0, 0);
            }
        }

        // ---- epilogue: 16 full 4-KB rows per strip, block-contiguous ----
        const size_t rowbase = (size_t)(s * NROWS + cm) * Ndim + wn;
#pragma unroll
        for (int nt = 0; nt < 8; ++nt) {
            floatx4 v;
            v.x = alpha * (float)acc[nt][0];
            v.y = alpha * (float)acc[nt][1];
            v.z = alpha * (float)acc[nt][2];
            v.w = alpha * (float)acc[nt][3];
            *(floatx4*)(Ob + rowbase + nt * 16 + cn) = v;
        }

        // bound wave drift: keep the write window a dense 64-KB strip
        __syncthreads();
    }
}

extern "C" void kernel_launch(void* const* d_in, const int* in_sizes, int n_in,
                              void* d_out, int out_size, void* d_ws, size_t ws_size,
                              hipStream_t stream) {
    const int*   a     = (const int*)d_in[0];
    const int*   b     = (const int*)d_in[1];
    const float* alpha = (const float*)d_in[2];
    float*       out   = (float*)d_out;

    const int batch = in_sizes[0] / (Mdim * Kdim);  // 64
    dim3 grid(batch, Mdim / (NROWS * NSTRIPS));     // (64, 4): 256 blocks = 1/CU
    bmm_s8_kernel<<<grid, 512, 0, stream>>>(a, b, alpha, out);
}

// Round 4
// 330.568 us; speedup vs baseline: 1.0492x; 1.0390x over previous
//
#include <hip/hip_runtime.h>

// BMM_S8T_S8N_F16T: out[b,m,n] = fp16-range(alpha * sum_k A[b,m,k]*B[b,n,k])
// A: (B,M,K) int32 (int8-range), B: (B,N,K) int32, out: float. B=64, M=N=1024, K=128.
//
// Roofline: 268 MB write + 67 MB read => ~53 us @6.3 TB/s. Write-dominated.
// R5/R6/R8: three structurally different schedules (per-iter barriers /
//   barrier-free wave-private / full-B-LDS + block-linear 1-MB streams) ALL
//   land at ~165 us kernel. Schedule-invariant => macro pattern irrelevant.
//   The one constant: every store instruction wrote 16 x 64-B HALF-LINE
//   segments at 4-KB stride (floatx4, 16 lanes/row-group), and all output
//   streamed through L2 with write-allocate. Suspect line-granularity
//   merge/RFO (+268 MB hidden reads) and/or L2 allocate thrash.
// R9: epilogue re-plumbed. Per strip, 4-row chunks (16 KB) are transposed
//   through LDS (XOR-swizzled, b128 both sides, conflict-free) and stored as
//   FULL-LINE 1-KB-contiguous-per-wave-instruction nontemporal stores --
//   byte-identical geometry to the 6.1-TB/s fill, bypassing L2 allocate.
//   Chunk barriers are raw lgkmcnt-only (LDS hazards only) so global stores
//   are NEVER vmcnt-drained inside the loop.

#define Mdim 1024
#define Ndim 1024
#define Kdim 128
#define NROWS 16     // m-rows per strip
#define NSTRIPS 16   // strips per block -> 256 m-rows
#define BSTRIDE 128  // packed bytes per B row (no pad; XOR swizzle instead)

using int32x4 = __attribute__((ext_vector_type(4))) int;
using floatx4 = __attribute__((ext_vector_type(4))) float;

__device__ __forceinline__ unsigned pack8(int32x4 v) {
    return (unsigned)(v.x & 255) | ((unsigned)(v.y & 255) << 8)
         | ((unsigned)(v.z & 255) << 16) | ((unsigned)(v.w & 255) << 24);
}

// B-tile swizzle: XOR row&7 into the 16-B-unit bits (bijective per row).
__device__ __forceinline__ int swz(int byte_off) {
    return byte_off ^ (((byte_off >> 7) & 7) << 4);
}

// LDS-only barrier: no vmcnt drain -> in-flight global stores keep streaming.
__device__ __forceinline__ void lds_barrier() {
    asm volatile("s_waitcnt lgkmcnt(0)\n\ts_barrier" ::: "memory");
}

__global__ __launch_bounds__(512, 2)
void bmm_s8_kernel(const int* __restrict__ A, const int* __restrict__ Bm,
                   const float* __restrict__ alpha_p, float* __restrict__ out)
{
    __shared__ unsigned char Bs[1024 * BSTRIDE];  // 128 KiB: full B, packed int8
    __shared__ int32x4 Cs4[1024];                 // 16 KiB: 4-row f32 chunk (transpose buf)
    unsigned char* const Cs = (unsigned char*)Cs4;

    const int t    = threadIdx.x;
    const int z    = blockIdx.x;   // batch; linear%8 == z%8 -> per-XCD batch affinity
    const int q    = blockIdx.y;   // m-quarter: rows [q*256, q*256+256)
    const int lane = t & 63;
    const int wave = t >> 6;       // 0..7
    const int wn   = wave * 128;   // this wave's n band

    const int* __restrict__ Ab = A  + (size_t)z * Mdim * Kdim + (size_t)(q * 256) * Kdim;
    const int* __restrict__ Bb = Bm + (size_t)z * Ndim * Kdim;
    float* __restrict__ Ob     = out + (size_t)z * Mdim * Ndim + (size_t)(q * 256) * Ndim;

    const int r = lane & 15;   // fragment row within 16 (m-row), also D col owner
    const int g = lane >> 4;   // fragment k-chunk selector, also D 4-col group

    // ---- issue A prefetch for strip 0 (oldest loads; land during staging) ----
    int32x4 araw[8];
#pragma unroll
    for (int k = 0; k < 8; ++k) {
        const int ks = k >> 2, i = k & 3;
        araw[k] = *(const int32x4*)(Ab + (size_t)r * Kdim + ks * 64 + g * 16 + i * 4);
    }

    // ---- stage FULL B (1024 rows x 32 16-B chunks = 32768 chunks) ----
#pragma unroll 1
    for (int rr = 0; rr < 4; ++rr) {
        int32x4 breg[16];
#pragma unroll
        for (int j = 0; j < 16; ++j) {
            const int f    = t + 512 * (rr * 16 + j);
            const int row  = f >> 5;
            const int colb = (f & 31) * 4;
            breg[j] = *(const int32x4*)(Bb + (size_t)row * Kdim + colb);
        }
#pragma unroll
        for (int j = 0; j < 16; ++j) {
            const int f    = t + 512 * (rr * 16 + j);
            const int row  = f >> 5;
            const int colb = (f & 31) * 4;
            *(unsigned*)(&Bs[swz(row * BSTRIDE + colb)]) = pack8(breg[j]);
        }
    }
    __syncthreads();

    const float alpha = alpha_p[0];

#pragma unroll 1
    for (int s = 0; s < NSTRIPS; ++s) {
        // consume prefetched A into fragments
        int32x4 af[2];
#pragma unroll
        for (int ks = 0; ks < 2; ++ks)
            af[ks] = (int32x4){ (int)pack8(araw[ks * 4 + 0]), (int)pack8(araw[ks * 4 + 1]),
                                (int)pack8(araw[ks * 4 + 2]), (int)pack8(araw[ks * 4 + 3]) };

        // issue next strip's A loads (in flight across compute + stores)
        if (s + 1 < NSTRIPS) {
            const int* __restrict__ An = Ab + (size_t)((s + 1) * NROWS) * Kdim;
#pragma unroll
            for (int k = 0; k < 8; ++k) {
                const int ks = k >> 2, i = k & 3;
                araw[k] = *(const int32x4*)(An + (size_t)r * Kdim + ks * 64 + g * 16 + i * 4);
            }
        }

        // ---- MFMA: wave computes 16(m) x 128(n) of this strip ----
        int32x4 acc[8];
#pragma unroll
        for (int nt = 0; nt < 8; ++nt)
            acc[nt] = (int32x4){0, 0, 0, 0};

#pragma unroll
        for (int ks = 0; ks < 2; ++ks) {
#pragma unroll
            for (int nt = 0; nt < 8; ++nt) {
                const int row = wn + nt * 16 + r;
                int32x4 bf = *(const int32x4*)(&Bs[swz(row * BSTRIDE + ks * 64 + g * 16)]);
                acc[nt] = __builtin_amdgcn_mfma_i32_16x16x64_i8(bf, af[ks], acc[nt], 0, 0, 0);
            }
        }

        // convert once: lane holds out[m=r][n = wn + nt*16 + g*4 + j]
        floatx4 facc[8];
#pragma unroll
        for (int nt = 0; nt < 8; ++nt) {
            facc[nt].x = alpha * (float)acc[nt][0];
            facc[nt].y = alpha * (float)acc[nt][1];
            facc[nt].z = alpha * (float)acc[nt][2];
            facc[nt].w = alpha * (float)acc[nt][3];
        }

        // ---- epilogue: 4 chunks of 4 rows; transpose via LDS, store as
        //      1-KB-contiguous-per-instruction nontemporal full-line writes ----
#pragma unroll
        for (int c = 0; c < 4; ++c) {
            if ((r >> 2) == c) {
                const int rowL = r & 3;
                const int xo   = (rowL & 3) << 4;
#pragma unroll
                for (int nt = 0; nt < 8; ++nt) {
                    const int off = rowL * 4096 + wn * 4 + nt * 64 + g * 16;
                    *(floatx4*)(&Cs[off ^ xo]) = facc[nt];
                }
            }
            lds_barrier();  // chunk data visible; stores below never drained here

            const size_t basef = (size_t)(s * NROWS + c * 4) * Ndim;  // float index
#pragma unroll
            for (int p = 0; p < 2; ++p) {
                const int off  = (t + p * 512) * 16;       // byte offset in 16-KB chunk
                const int rowL = off >> 12;
                floatx4 v = *(const floatx4*)(&Cs[off ^ ((rowL & 3) << 4)]);
                __builtin_nontemporal_store(v, (floatx4*)(Ob + basef + (off >> 2)));
            }
            lds_barrier();  // reads done before next chunk overwrites Cs
        }
    }
}

extern "C" void kernel_launch(void* const* d_in, const int* in_sizes, int n_in,
                              void* d_out, int out_size, void* d_ws, size_t ws_size,
                              hipStream_t stream) {
    const int*   a     = (const int*)d_in[0];
    const int*   b     = (const int*)d_in[1];
    const float* alpha = (const float*)d_in[2];
    float*       out   = (float*)d_out;

    const int batch = in_sizes[0] / (Mdim * Kdim);  // 64
    dim3 grid(batch, Mdim / (NROWS * NSTRIPS));     // (64, 4): 256 blocks = 1/CU
    bmm_s8_kernel<<<grid, 512, 0, stream>>>(a, b, alpha, out);
}